// Round 7
// baseline (57.386 us; speedup 1.0000x reference)
//
#include <hip/hip_runtime.h>

#define HIDDEN 64
#define BSN 256          // nodes per bucket (power of 2)
#define LOGB 8
#define NTILES 256       // sort tiles (== scanA block size)
#define NTS 1024         // threads for hist/sort kernels
#define NTE 256          // threads for bucket (edge) kernels == BSN
#define MAXB 4096        // max buckets supported by LDS counters (16 KB)
#define SRCBITS 17       // src id fits in 17 bits (n <= 131072)
#define SENT 0xFFFFFFFFu

__device__ __forceinline__ int wave_incl_scan(int v) {
    const int lane = threadIdx.x & 63;
#pragma unroll
    for (int off = 1; off < 64; off <<= 1) {
        int u = __shfl_up(v, off, 64);
        if (lane >= off) v += u;
    }
    return v;
}

// ---------- pass 1: per-tile per-bucket histogram --------------------------
__global__ __launch_bounds__(NTS) void k_hist(const int* __restrict__ dst, int e,
                                              int nbuck, int* __restrict__ counts) {
    __shared__ int lcnt[MAXB];
    const int t = blockIdx.x;
    for (int i = threadIdx.x; i < nbuck; i += NTS) lcnt[i] = 0;
    __syncthreads();
    const int Q = e >> 2;
    const int qlo = (int)((long long)Q * t / NTILES);
    const int qhi = (int)((long long)Q * (t + 1) / NTILES);
    for (int q = qlo + threadIdx.x; q < qhi; q += NTS) {
        int4 d4 = ((const int4*)dst)[q];
        atomicAdd(&lcnt[d4.x >> LOGB], 1);
        atomicAdd(&lcnt[d4.y >> LOGB], 1);
        atomicAdd(&lcnt[d4.z >> LOGB], 1);
        atomicAdd(&lcnt[d4.w >> LOGB], 1);
    }
    if (t == 0) {  // tail edges (e % 4) counted by tile 0
        for (int i = (Q << 2) + threadIdx.x; i < e; i += NTS)
            atomicAdd(&lcnt[dst[i] >> LOGB], 1);
    }
    __syncthreads();
    for (int g = threadIdx.x; g < nbuck; g += NTS)
        counts[g * NTILES + t] = lcnt[g];
}

// ---------- pass 2a: within-bucket exclusive scan (wave shfl) --------------
__global__ __launch_bounds__(NTILES) void k_scanA(const int* __restrict__ counts,
                                                  int* __restrict__ locoffs,
                                                  int* __restrict__ totals) {
    __shared__ int wtot[NTILES / 64];
    const int g = blockIdx.x;
    const int t = threadIdx.x;
    int c = counts[g * NTILES + t];
    int inc = wave_incl_scan(c);
    if ((t & 63) == 63) wtot[t >> 6] = inc;
    __syncthreads();
    int add = 0;
    const int w = t >> 6;
    for (int i = 0; i < w; ++i) add += wtot[i];
    locoffs[g * NTILES + t] = inc + add - c;       // exclusive within bucket
    if (t == NTILES - 1) totals[g] = inc + add;    // bucket total
}

// ---------- pass 2b: scan padded totals -> bstart; fill pad sentinels ------
__global__ __launch_bounds__(256) void k_scanB(const int* __restrict__ totals,
                                               int* __restrict__ bstart,
                                               unsigned* __restrict__ sw,
                                               int nbuck) {
    __shared__ int wtot[4];
    const int t = threadIdx.x;
    const int chunk = (nbuck + 255) / 256;
    const int lo = t * chunk;
    const int hi = (lo + chunk < nbuck) ? lo + chunk : nbuck;
    int s = 0;
    for (int i = lo; i < hi; ++i) s += (totals[i] + 3) & ~3;
    int inc = wave_incl_scan(s);
    if ((t & 63) == 63) wtot[t >> 6] = inc;
    __syncthreads();
    int add = 0;
    for (int i = 0; i < (t >> 6); ++i) add += wtot[i];
    int run = inc + add - s;   // exclusive over chunks (padded)
    for (int i = lo; i < hi; ++i) {
        bstart[i] = run;
        int tot = totals[i], totp = (tot + 3) & ~3;
        for (int p = run + tot; p < run + totp; ++p) sw[p] = SENT;
        run += totp;
    }
    if (hi == nbuck && lo <= hi) bstart[nbuck] = run;
}

// ---------- pass 3: scatter edges into bucket-sorted packed words ----------
__global__ __launch_bounds__(NTS) void k_sortB(const int* __restrict__ src,
                                               const int* __restrict__ dst, int e,
                                               int nbuck,
                                               const int* __restrict__ locoffs,
                                               const int* __restrict__ bstart,
                                               unsigned* __restrict__ sw) {
    __shared__ int loffs[MAXB];
    const int t = blockIdx.x;
    for (int g = threadIdx.x; g < nbuck; g += NTS)
        loffs[g] = bstart[g] + locoffs[g * NTILES + t];
    __syncthreads();
    const int Q = e >> 2;
    const int qlo = (int)((long long)Q * t / NTILES);
    const int qhi = (int)((long long)Q * (t + 1) / NTILES);
    for (int q = qlo + threadIdx.x; q < qhi; q += NTS) {
        int4 s4 = ((const int4*)src)[q];
        int4 d4 = ((const int4*)dst)[q];
        { int d = d4.x, g = d >> LOGB; int pos = atomicAdd(&loffs[g], 1);
          sw[pos] = ((unsigned)(d & (BSN - 1)) << SRCBITS) | (unsigned)s4.x; }
        { int d = d4.y, g = d >> LOGB; int pos = atomicAdd(&loffs[g], 1);
          sw[pos] = ((unsigned)(d & (BSN - 1)) << SRCBITS) | (unsigned)s4.y; }
        { int d = d4.z, g = d >> LOGB; int pos = atomicAdd(&loffs[g], 1);
          sw[pos] = ((unsigned)(d & (BSN - 1)) << SRCBITS) | (unsigned)s4.z; }
        { int d = d4.w, g = d >> LOGB; int pos = atomicAdd(&loffs[g], 1);
          sw[pos] = ((unsigned)(d & (BSN - 1)) << SRCBITS) | (unsigned)s4.w; }
    }
    if (t == 0) {  // tail edges
        for (int i = (Q << 2) + threadIdx.x; i < e; i += NTS) {
            int d = dst[i], g = d >> LOGB;
            int pos = atomicAdd(&loffs[g], 1);
            sw[pos] = ((unsigned)(d & (BSN - 1)) << SRCBITS) | (unsigned)src[i];
        }
    }
}

// ---------- pass 4: degree -> dinv, xs  (one block per bucket) -------------
__global__ __launch_bounds__(NTE) void k_deg_prep(const unsigned* __restrict__ sw,
                                                  const int* __restrict__ bstart,
                                                  const float* __restrict__ x,
                                                  float* __restrict__ dinv,
                                                  float* __restrict__ xs, int n) {
    __shared__ float lacc[BSN];
    const int g = blockIdx.x;
    lacc[threadIdx.x] = 0.0f;
    __syncthreads();
    const int qlo = bstart[g] >> 2, qhi = bstart[g + 1] >> 2;
    for (int q = qlo + threadIdx.x; q < qhi; q += NTE) {
        uint4 w4 = ((const uint4*)sw)[q];
        unsigned l0 = w4.x >> SRCBITS; if (l0 < BSN) atomicAdd(&lacc[l0], 1.0f);
        unsigned l1 = w4.y >> SRCBITS; if (l1 < BSN) atomicAdd(&lacc[l1], 1.0f);
        unsigned l2 = w4.z >> SRCBITS; if (l2 < BSN) atomicAdd(&lacc[l2], 1.0f);
        unsigned l3 = w4.w >> SRCBITS; if (l3 < BSN) atomicAdd(&lacc[l3], 1.0f);
    }
    __syncthreads();
    const int node = (g << LOGB) + threadIdx.x;
    if (node < n) {
        float d = rsqrtf(1.0f + lacc[threadIdx.x]);   // +1 = self-loop
        dinv[node] = d;
        xs[node] = x[node] * d;
    }
}

// ---------- pass 5: scatter xs -> agg -> MLP -> h2s ------------------------
__global__ __launch_bounds__(NTE) void k_scat_mlp(const unsigned* __restrict__ sw,
    const int* __restrict__ bstart, const float* __restrict__ dinv,
    const float* __restrict__ xs, const float* __restrict__ W1,
    const float* __restrict__ b1, const float* __restrict__ W2,
    float* __restrict__ h2s, int n) {
    __shared__ float lacc[BSN];
    __shared__ float swt[3 * HIDDEN];
    const int g = blockIdx.x;
    lacc[threadIdx.x] = 0.0f;
    if (threadIdx.x < 3 * HIDDEN) {
        int j = threadIdx.x;
        swt[j] = (j < HIDDEN) ? W1[j]
               : (j < 2 * HIDDEN) ? b1[j - HIDDEN] : W2[j - 2 * HIDDEN];
    }
    __syncthreads();
    const int qlo = bstart[g] >> 2, qhi = bstart[g + 1] >> 2;
    const unsigned SM = (1u << SRCBITS) - 1;
    for (int q = qlo + threadIdx.x; q < qhi; q += NTE) {
        uint4 w4 = ((const uint4*)sw)[q];
        unsigned l0 = w4.x >> SRCBITS; if (l0 < BSN) atomicAdd(&lacc[l0], xs[w4.x & SM]);
        unsigned l1 = w4.y >> SRCBITS; if (l1 < BSN) atomicAdd(&lacc[l1], xs[w4.y & SM]);
        unsigned l2 = w4.z >> SRCBITS; if (l2 < BSN) atomicAdd(&lacc[l2], xs[w4.z & SM]);
        unsigned l3 = w4.w >> SRCBITS; if (l3 < BSN) atomicAdd(&lacc[l3], xs[w4.w & SM]);
    }
    __syncthreads();
    const int node = (g << LOGB) + threadIdx.x;
    if (node < n) {
        float di = dinv[node];
        float s1 = di * (lacc[threadIdx.x] + xs[node]);  // xs = self-loop term
        float h = 0.0f;
#pragma unroll
        for (int j = 0; j < HIDDEN; ++j)
            h += fmaxf(fmaf(s1, swt[j], swt[HIDDEN + j]), 0.0f) * swt[2 * HIDDEN + j];
        h2s[node] = h * di;
    }
}

// ---------- pass 6: scatter h2s -> agg -> out ------------------------------
__global__ __launch_bounds__(NTE) void k_scat_out(const unsigned* __restrict__ sw,
    const int* __restrict__ bstart, const float* __restrict__ dinv,
    const float* __restrict__ h2s, const float* __restrict__ b2,
    float* __restrict__ out, int n) {
    __shared__ float lacc[BSN];
    const int g = blockIdx.x;
    lacc[threadIdx.x] = 0.0f;
    __syncthreads();
    const int qlo = bstart[g] >> 2, qhi = bstart[g + 1] >> 2;
    const unsigned SM = (1u << SRCBITS) - 1;
    for (int q = qlo + threadIdx.x; q < qhi; q += NTE) {
        uint4 w4 = ((const uint4*)sw)[q];
        unsigned l0 = w4.x >> SRCBITS; if (l0 < BSN) atomicAdd(&lacc[l0], h2s[w4.x & SM]);
        unsigned l1 = w4.y >> SRCBITS; if (l1 < BSN) atomicAdd(&lacc[l1], h2s[w4.y & SM]);
        unsigned l2 = w4.z >> SRCBITS; if (l2 < BSN) atomicAdd(&lacc[l2], h2s[w4.z & SM]);
        unsigned l3 = w4.w >> SRCBITS; if (l3 < BSN) atomicAdd(&lacc[l3], h2s[w4.w & SM]);
    }
    __syncthreads();
    const int node = (g << LOGB) + threadIdx.x;
    if (node < n)
        out[node] = dinv[node] * (lacc[threadIdx.x] + h2s[node]) + b2[0];
}

// ---------------- fallback: single-copy global-atomic path ----------------
__global__ void f_init(float* deg, float* agg, int n) {
    int i = blockIdx.x * blockDim.x + threadIdx.x;
    if (i < n) { deg[i] = 1.0f; agg[i] = 0.0f; }
}
__global__ void f_deg(const int* __restrict__ dst, float* deg, int e) {
    int i = blockIdx.x * blockDim.x + threadIdx.x;
    if (i < e) atomicAdd(&deg[dst[i]], 1.0f);
}
__global__ void f_prep(const float* __restrict__ x, float* deg,
                       float* __restrict__ xs, int n) {
    int i = blockIdx.x * blockDim.x + threadIdx.x;
    if (i < n) { float d = rsqrtf(deg[i]); deg[i] = d; xs[i] = x[i] * d; }
}
__global__ void f_scat(const int* __restrict__ src, const int* __restrict__ dst,
                       const float* __restrict__ vals, float* agg, int e) {
    int i = blockIdx.x * blockDim.x + threadIdx.x;
    if (i < e) atomicAdd(&agg[dst[i]], vals[src[i]]);
}
__global__ void f_mlp(const float* __restrict__ dinv, const float* __restrict__ xs,
                      float* agg, const float* __restrict__ W1,
                      const float* __restrict__ b1, const float* __restrict__ W2,
                      float* __restrict__ h2s, int n) {
    __shared__ float sW1[HIDDEN], sb1[HIDDEN], sW2[HIDDEN];
    if (threadIdx.x < HIDDEN) {
        sW1[threadIdx.x] = W1[threadIdx.x];
        sb1[threadIdx.x] = b1[threadIdx.x];
        sW2[threadIdx.x] = W2[threadIdx.x];
    }
    __syncthreads();
    int i = blockIdx.x * blockDim.x + threadIdx.x;
    if (i >= n) return;
    float di = dinv[i];
    float s1 = di * (agg[i] + xs[i]);
    agg[i] = 0.0f;
    float h = 0.0f;
#pragma unroll
    for (int j = 0; j < HIDDEN; ++j)
        h += fmaxf(fmaf(s1, sW1[j], sb1[j]), 0.0f) * sW2[j];
    h2s[i] = h * di;
}
__global__ void f_out(const float* __restrict__ dinv, const float* __restrict__ h2s,
                      const float* __restrict__ agg, const float* __restrict__ b2,
                      float* __restrict__ out, int n) {
    int i = blockIdx.x * blockDim.x + threadIdx.x;
    if (i < n) out[i] = dinv[i] * (agg[i] + h2s[i]) + b2[0];
}

// ---------------------------------------------------------------------------
extern "C" void kernel_launch(void* const* d_in, const int* in_sizes, int n_in,
                              void* d_out, int out_size, void* d_ws, size_t ws_size,
                              hipStream_t stream) {
    const float* x  = (const float*)d_in[0];
    const int*   ei = (const int*)d_in[1];   // [2, E] int32
    const float* W1 = (const float*)d_in[2];
    const float* b1 = (const float*)d_in[3];
    const float* W2 = (const float*)d_in[4];
    const float* b2 = (const float*)d_in[5];
    float* out = (float*)d_out;

    const int n = in_sizes[0];
    const int e = in_sizes[1] / 2;
    const int* src = ei;
    const int* dst = ei + e;

    const int nbuck = (n + BSN - 1) >> LOGB;
    const int M = nbuck * NTILES;
    // ws: dinv[n], xs[n], h2s[n] | sw[e + 4*nbuck] | counts[M], locoffs[M],
    //     totals[nbuck], bstart[nbuck+1]
    const size_t need = ((size_t)3 * n + (size_t)e + 4 * nbuck + 2 * (size_t)M
                         + 2 * nbuck + 1) * sizeof(int);

    if (nbuck >= 1 && nbuck <= MAXB && n <= (1 << SRCBITS) && ws_size >= need) {
        float* dinv    = (float*)d_ws;
        float* xs      = dinv + n;
        float* h2s     = xs + n;
        unsigned* sw   = (unsigned*)(h2s + n);
        int* counts    = (int*)(sw + e + 4 * nbuck);
        int* locoffs   = counts + M;
        int* totals    = locoffs + M;
        int* bstart    = totals + nbuck;

        k_hist    <<<NTILES, NTS,    0, stream>>>(dst, e, nbuck, counts);
        k_scanA   <<<nbuck,  NTILES, 0, stream>>>(counts, locoffs, totals);
        k_scanB   <<<1,      256,    0, stream>>>(totals, bstart, sw, nbuck);
        k_sortB   <<<NTILES, NTS,    0, stream>>>(src, dst, e, nbuck, locoffs,
                                                  bstart, sw);
        k_deg_prep<<<nbuck,  NTE,    0, stream>>>(sw, bstart, x, dinv, xs, n);
        k_scat_mlp<<<nbuck,  NTE,    0, stream>>>(sw, bstart, dinv, xs,
                                                  W1, b1, W2, h2s, n);
        k_scat_out<<<nbuck,  NTE,    0, stream>>>(sw, bstart, dinv, h2s,
                                                  b2, out, n);
    } else {
        const int BT = 256;
        const int gn = (n + BT - 1) / BT;
        const int ge = (e + BT - 1) / BT;
        float* dinv = (float*)d_ws;   // holds deg then dinv
        float* xs   = dinv + n;
        float* h2s  = xs + n;
        float* agg  = h2s + n;
        f_init<<<gn, BT, 0, stream>>>(dinv, agg, n);
        f_deg <<<ge, BT, 0, stream>>>(dst, dinv, e);
        f_prep<<<gn, BT, 0, stream>>>(x, dinv, xs, n);
        f_scat<<<ge, BT, 0, stream>>>(src, dst, xs, agg, e);
        f_mlp <<<gn, BT, 0, stream>>>(dinv, xs, agg, W1, b1, W2, h2s, n);
        f_scat<<<ge, BT, 0, stream>>>(src, dst, h2s, agg, e);
        f_out <<<gn, BT, 0, stream>>>(dinv, h2s, agg, b2, out, n);
    }
}